// Round 1
// baseline (228.806 us; speedup 1.0000x reference)
//
#include <hip/hip_runtime.h>

// LinearLIFBlock: cur = X[16384x1024] * W^T[1024x1024]; LIF scan over t (64 steps).
// R10: 2-phase double-buffered pipeline (guide T3 minimum recipe). 512-thread
// blocks (8 waves), 128x256 tile, wave tile 64x64 (acc[4][4]), LDS 2x48KB
// buffers (96 KB, 1 block/CU, still 2 waves/SIMD). Per k-tile: issue next
// tile's 6 global_load_lds, then ds_read+96... 48*3 MFMA on current buffer,
// one __syncthreads() drain at tile end -> staging latency hides under the
// MFMA phase instead of serializing before it (R9: stage->drain->compute,
// MfmaUtil 26%). Distinct static buf0/buf1 arrays + unroll-by-2 so the
// compiler can disambiguate gload_lds writes from ds_reads. setprio(1)
// around MFMA cluster. XOR swizzle (0 conflicts, R5/R7-validated) and the
// in-register LIF shfl relay are unchanged except j:8->4, wn stride 128->64.
// Margin 6e-5 flagged columns get exact fp64 fixup.

#define T_DIM 64
#define B_DIM 256
#define F_DIM 1024
#define K_DIM 1024
#define M_DIM 16384            // T*B
#define COLS  (B_DIM * F_DIM)  // 262144 scan columns
#define KP    2048             // packed K: [hi | lo]
#define MARGIN 6e-5f
#define LIST_CAP 32768

typedef __attribute__((ext_vector_type(8))) short short8;
typedef __attribute__((ext_vector_type(4))) float floatx4;

#define ASYNC_CP16(gp, lp)                                                     \
    __builtin_amdgcn_global_load_lds(                                          \
        (const __attribute__((address_space(1))) unsigned int*)(gp),           \
        (__attribute__((address_space(3))) unsigned int*)(lp), 16, 0, 0)

// ---------------------------------------------------------------- bf16 split
__device__ inline unsigned short f32_to_bf16_rne(float f) {
    unsigned int u = __builtin_bit_cast(unsigned int, f);
    unsigned int r = (u + 0x7FFFu + ((u >> 16) & 1u)) >> 16;
    return (unsigned short)r;
}
__device__ inline float bf16_to_f32(unsigned short h) {
    unsigned int u = ((unsigned int)h) << 16;
    return __builtin_bit_cast(float, u);
}

// Fused split: blocks [0,16384) do X (+row remap to b*64+t), [16384,17408) do W.
// Also zeroes the fixup counter (blk 0).
__global__ __launch_bounds__(256) void split_kernel(
    const float* __restrict__ x, const float* __restrict__ Wm,
    unsigned short* __restrict__ A, unsigned short* __restrict__ B,
    unsigned int* __restrict__ counter)
{
    if (blockIdx.x == 0 && threadIdx.x == 0) *counter = 0;
    const int blk = blockIdx.x;
    const float* in;
    unsigned short* dst;
    int g;
    int orow;
    if (blk < 16384) {
        g = blk * 256 + threadIdx.x;          // float4 index into x
        int e = g * 4;
        int row = e >> 10;                    // t*256 + b
        orow = ((row & 255) << 6) | (row >> 8);  // b*64 + t
        in = x; dst = A;
    } else {
        g = (blk - 16384) * 256 + threadIdx.x;
        int e = g * 4;
        orow = e >> 10;                       // o
        in = Wm; dst = B;
    }
    int k = (g * 4) & 1023;
    float4 v = reinterpret_cast<const float4*>(in)[g];
    ushort4 h, l;
    float f;
    f = v.x; h.x = f32_to_bf16_rne(f); l.x = f32_to_bf16_rne(f - bf16_to_f32(h.x));
    f = v.y; h.y = f32_to_bf16_rne(f); l.y = f32_to_bf16_rne(f - bf16_to_f32(h.y));
    f = v.z; h.z = f32_to_bf16_rne(f); l.z = f32_to_bf16_rne(f - bf16_to_f32(h.z));
    f = v.w; h.w = f32_to_bf16_rne(f); l.w = f32_to_bf16_rne(f - bf16_to_f32(h.w));
    reinterpret_cast<ushort4*>(dst)[(size_t)orow * (KP / 4) + (k >> 2)] = h;
    reinterpret_cast<ushort4*>(dst)[(size_t)orow * (KP / 4) + 256 + (k >> 2)] = l;
}

// ----------------------------------------------- fused MFMA GEMM + LIF scan
// Block tile 128(M) x 256(N); 512 threads (8 waves, 2M x 4N), wave 64x64.
// 2-phase dbuf: while computing buf[p], buf[p^1] is being filled by
// global_load_lds issued BEFORE the compute phase; single barrier per k-tile.
//   cur = A.hi*B.hi + A.lo*B.hi + A.hi*B.lo
__global__ __launch_bounds__(512, 2) void gemm_scan_kernel(
    const unsigned short* __restrict__ A,  // [16384][2048], rows b*64+t
    const unsigned short* __restrict__ B,  // [1024][2048],  rows o
    float* __restrict__ out,
    unsigned int* __restrict__ counter, unsigned int* __restrict__ list)
{
    __shared__ unsigned short Ah0[128 * 32], Al0[128 * 32];  // 16 KB
    __shared__ unsigned short Bh0[256 * 32], Bl0[256 * 32];  // 32 KB
    __shared__ unsigned short Ah1[128 * 32], Al1[128 * 32];  // 16 KB
    __shared__ unsigned short Bh1[256 * 32], Bl1[256 * 32];  // 32 KB

    const int tid  = threadIdx.x;
    const int lane = tid & 63;
    const int wv   = tid >> 6;                       // 0..7
    // XCD-aware: XCD = lid&7 owns a contiguous 16-mt stripe; nt varies fastest.
    const int lid = blockIdx.x;                      // 0..511
    const int mt  = ((lid & 7) << 4) | (lid >> 5);   // 0..127
    const int nt  = (lid >> 3) & 3;                  // 0..3
    const int m0  = mt * 128;
    const int n0  = nt * 256;
    const int wm  = (wv & 1) * 64;
    const int wn  = (wv >> 1) * 64;

    floatx4 acc[4][4] = {};

    // Staging with source-side XOR chunk swizzle (R5/R7-validated: 0 conflicts).
    const int srow = tid >> 2;                      // 0..127 staging row
    const int slin = (tid & 3) * 8;                 // linear LDS chunk (dest)
    const int ssw  = (((tid & 3) ^ ((srow >> 1) & 3)) * 8);  // swizzled source chunk
    const int lrow = lane & 15;
    const int q    = lane >> 4;                     // 0..3
    const int rsw  = (lrow >> 1) & 3;               // read-side swizzle key
    const int sl   = (q ^ rsw) * 8;

    const unsigned short* Ab = A + (size_t)m0 * KP;
    const unsigned short* Bb = B + (size_t)n0 * KP;

    // global source pointers (per-lane, pre-swizzled)
    const unsigned short* ga_h  = Ab + (size_t)srow * KP + ssw;
    const unsigned short* ga_l  = ga_h + 1024;
    const unsigned short* gb0_h = Bb + (size_t)srow * KP + ssw;
    const unsigned short* gb0_l = gb0_h + 1024;
    const unsigned short* gb1_h = gb0_h + (size_t)128 * KP;
    const unsigned short* gb1_l = gb1_h + 1024;

    // LDS dest offsets (lane-linear within each wave: lane -> base + lane*16B)
    const int ldsA  = srow * 32 + slin;
    const int ldsB1 = (srow + 128) * 32 + slin;

    // fragment read offsets
    int aoff[4], boff[4];
#pragma unroll
    for (int i = 0; i < 4; ++i) aoff[i] = (wm + i * 16 + lrow) * 32 + sl;
#pragma unroll
    for (int j = 0; j < 4; ++j) boff[j] = (wn + j * 16 + lrow) * 32 + sl;

#define STAGE(AhB, AlB, BhB, BlB, kk) do {                                     \
        ASYNC_CP16(ga_h + (kk),  &AhB[ldsA]);                                  \
        ASYNC_CP16(ga_l + (kk),  &AlB[ldsA]);                                  \
        ASYNC_CP16(gb0_h + (kk), &BhB[ldsA]);                                  \
        ASYNC_CP16(gb1_h + (kk), &BhB[ldsB1]);                                 \
        ASYNC_CP16(gb0_l + (kk), &BlB[ldsA]);                                  \
        ASYNC_CP16(gb1_l + (kk), &BlB[ldsB1]);                                 \
    } while (0)

#define COMPUTE(AhB, AlB, BhB, BlB) do {                                       \
        short8 ah[4], al[4], bh[4], bl[4];                                     \
        _Pragma("unroll")                                                      \
        for (int i = 0; i < 4; ++i) {                                          \
            ah[i] = *reinterpret_cast<const short8*>(&AhB[aoff[i]]);           \
            al[i] = *reinterpret_cast<const short8*>(&AlB[aoff[i]]);           \
        }                                                                      \
        _Pragma("unroll")                                                      \
        for (int j = 0; j < 4; ++j) {                                          \
            bh[j] = *reinterpret_cast<const short8*>(&BhB[boff[j]]);           \
            bl[j] = *reinterpret_cast<const short8*>(&BlB[boff[j]]);           \
        }                                                                      \
        __builtin_amdgcn_s_setprio(1);                                         \
        _Pragma("unroll")                                                      \
        for (int i = 0; i < 4; ++i)                                            \
            _Pragma("unroll")                                                  \
            for (int j = 0; j < 4; ++j)                                        \
                acc[i][j] = __builtin_amdgcn_mfma_f32_16x16x32_bf16(           \
                    ah[i], bh[j], acc[i][j], 0, 0, 0);                         \
        _Pragma("unroll")                                                      \
        for (int i = 0; i < 4; ++i)                                            \
            _Pragma("unroll")                                                  \
            for (int j = 0; j < 4; ++j)                                        \
                acc[i][j] = __builtin_amdgcn_mfma_f32_16x16x32_bf16(           \
                    al[i], bh[j], acc[i][j], 0, 0, 0);                         \
        _Pragma("unroll")                                                      \
        for (int i = 0; i < 4; ++i)                                            \
            _Pragma("unroll")                                                  \
            for (int j = 0; j < 4; ++j)                                        \
                acc[i][j] = __builtin_amdgcn_mfma_f32_16x16x32_bf16(           \
                    ah[i], bl[j], acc[i][j], 0, 0, 0);                         \
        __builtin_amdgcn_s_setprio(0);                                         \
    } while (0)

    // prologue: fill buf0 for k-tile 0
    STAGE(Ah0, Al0, Bh0, Bl0, 0);
    __syncthreads();   // drains vmcnt(0): buf0 ready

#pragma unroll 1
    for (int kt = 0; kt < 32; kt += 2) {
        // phase A: stage tile kt+1 into buf1, compute tile kt from buf0
        STAGE(Ah1, Al1, Bh1, Bl1, (kt + 1) * 32);
        COMPUTE(Ah0, Al0, Bh0, Bl0);
        __syncthreads();   // drains vmcnt: buf1 ready; buf0 free to overwrite
        // phase B: stage tile kt+2 into buf0, compute tile kt+1 from buf1
        if (kt + 2 < 32) STAGE(Ah0, Al0, Bh0, Bl0, (kt + 2) * 32);
        COMPUTE(Ah1, Al1, Bh1, Bl1);
        __syncthreads();
    }

#undef STAGE
#undef COMPUTE

    // ---- fused LIF scan in registers (validated relay) ----
    // Wave owns all 64 t of batch b = mt*2 + (wv&1), cols o = n0+wn+j*16+col.
    // acc[i][j][r] = cur at t = i*16 + q*4 + r, col = lane&15.
    const int col = lane & 15;
    const int b_g = mt * 2 + (wv & 1);

    unsigned int fmask = 0;
#pragma unroll
    for (int j = 0; j < 4; ++j) {
        float v = 0.f;
        bool fl = false;
#pragma unroll
        for (int i = 0; i < 4; ++i) {
#pragma unroll
            for (int qq = 0; qq < 4; ++qq) {
                if (q == qq) {
#pragma unroll
                    for (int r = 0; r < 4; ++r) {
                        float cu = acc[i][j][r];
                        float h = v + (cu - v) * 0.5f;
                        float d = h - 1.0f;
                        bool sp = (d >= 0.f);
                        fl |= (fabsf(d) < MARGIN);
                        acc[i][j][r] = sp ? 1.0f : 0.0f;  // spike overwrites cur
                        v = sp ? 0.f : h;
                    }
                }
                v = __shfl(v, qq * 16 + col, 64);  // broadcast owner's v
            }
        }
        if (fl) fmask |= (1u << j);
    }
    fmask |= __shfl_xor(fmask, 16, 64);
    fmask |= __shfl_xor(fmask, 32, 64);

    // spike stores
    float* outp = out + (size_t)b_g * F_DIM;
#pragma unroll
    for (int i = 0; i < 4; ++i)
#pragma unroll
        for (int j = 0; j < 4; ++j)
#pragma unroll
            for (int r = 0; r < 4; ++r) {
                int t = i * 16 + q * 4 + r;
                int o = n0 + wn + j * 16 + col;
                outp[(size_t)t * COLS + o] = acc[i][j][r];
            }

    if (q == 0 && fmask) {
        for (int j = 0; j < 4; ++j)
            if (fmask & (1u << j)) {
                unsigned int idx = atomicAdd(counter, 1u);
                if (idx < LIST_CAP)
                    list[idx] = (unsigned int)((b_g << 10) | (n0 + wn + j * 16 + col));
            }
    }
}

// ------------------------------------------------------- exact fp64 fixup
__global__ __launch_bounds__(256) void fixup_kernel(
    const float* __restrict__ x, const float* __restrict__ W,
    const unsigned int* __restrict__ counter, const unsigned int* __restrict__ list,
    float* __restrict__ out)
{
    __shared__ double curd[T_DIM];
    __shared__ float wrow[K_DIM];
    unsigned int n = *counter;
    if (n > LIST_CAP) n = LIST_CAP;
    const int wv = threadIdx.x >> 6, lane = threadIdx.x & 63;

    for (unsigned int idx = blockIdx.x; idx < n; idx += gridDim.x) {
        const unsigned int c = list[idx];
        const int b = c >> 10, o = c & 1023;
        __syncthreads();
        for (int k = threadIdx.x; k < K_DIM; k += 256) wrow[k] = W[(size_t)o * K_DIM + k];
        __syncthreads();
        for (int it = 0; it < 16; ++it) {
            const int t = it * 4 + wv;
            const float* xp = x + (size_t)t * COLS + (size_t)b * F_DIM + lane * 16;
            double s = 0.0;
#pragma unroll
            for (int qq = 0; qq < 4; ++qq) {
                float4 xv = reinterpret_cast<const float4*>(xp)[qq];
                float4 wq = *reinterpret_cast<const float4*>(&wrow[lane * 16 + qq * 4]);
                s += (double)xv.x * (double)wq.x + (double)xv.y * (double)wq.y +
                     (double)xv.z * (double)wq.z + (double)xv.w * (double)wq.w;
            }
#pragma unroll
            for (int off = 32; off > 0; off >>= 1) s += __shfl_down(s, off, 64);
            if (lane == 0) curd[t] = s;
        }
        __syncthreads();
        if (threadIdx.x == 0) {
            double v = 0.0;
            for (int t = 0; t < T_DIM; ++t) {
                double h = v + (curd[t] - v) * 0.5;
                bool s = (h >= 1.0);
                out[(size_t)t * COLS + c] = s ? 1.0f : 0.0f;
                v = s ? 0.0 : h;
            }
        }
        __syncthreads();
    }
}

// --------------------------------------------------- fp64 fallback (round-1)
#define TILE 64
#define KC 32
#define XS_LD 36
#define SC_LD 65

__global__ __launch_bounds__(256) void lif_fused_kernel(
    const float* __restrict__ x, const float* __restrict__ Wm, float* __restrict__ out)
{
    __shared__ __align__(16) unsigned char smem_raw[TILE * SC_LD * sizeof(double)];
    float* sf = reinterpret_cast<float*>(smem_raw);
    double* sd = reinterpret_cast<double*>(smem_raw);
    float* Xs = sf;
    float* Ws = sf + TILE * XS_LD;

    const int b = blockIdx.y;
    const int o0 = blockIdx.x * TILE;
    const int tid = threadIdx.x;
    const int tx = tid & 15, ty = tid >> 4;

    double acc[4][4];
#pragma unroll
    for (int i = 0; i < 4; ++i)
#pragma unroll
        for (int j = 0; j < 4; ++j) acc[i][j] = 0.0;

    const int r = tid >> 3, c4 = (tid & 7) * 4;
    const float* xbase = x + (size_t)b * F_DIM;

    for (int k0 = 0; k0 < K_DIM; k0 += KC) {
        __syncthreads();
        float4 xv0 = *reinterpret_cast<const float4*>(xbase + (size_t)r * COLS + k0 + c4);
        float4 xv1 = *reinterpret_cast<const float4*>(xbase + (size_t)(r + 32) * COLS + k0 + c4);
        *reinterpret_cast<float4*>(Xs + r * XS_LD + c4) = xv0;
        *reinterpret_cast<float4*>(Xs + (r + 32) * XS_LD + c4) = xv1;
        float4 wv0 = *reinterpret_cast<const float4*>(Wm + (size_t)(o0 + r) * K_DIM + k0 + c4);
        float4 wv1 = *reinterpret_cast<const float4*>(Wm + (size_t)(o0 + r + 32) * K_DIM + k0 + c4);
        *reinterpret_cast<float4*>(Ws + r * XS_LD + c4) = wv0;
        *reinterpret_cast<float4*>(Ws + (r + 32) * XS_LD + c4) = wv1;
        __syncthreads();
#pragma unroll 4
        for (int kk = 0; kk < KC; ++kk) {
            double xa[4], wb[4];
#pragma unroll
            for (int i = 0; i < 4; ++i) xa[i] = (double)Xs[(4 * ty + i) * XS_LD + kk];
#pragma unroll
            for (int j = 0; j < 4; ++j) wb[j] = (double)Ws[(4 * tx + j) * XS_LD + kk];
#pragma unroll
            for (int i = 0; i < 4; ++i)
#pragma unroll
                for (int j = 0; j < 4; ++j) acc[i][j] = fma(xa[i], wb[j], acc[i][j]);
        }
    }
    __syncthreads();
#pragma unroll
    for (int i = 0; i < 4; ++i)
#pragma unroll
        for (int j = 0; j < 4; ++j) sd[(4 * ty + i) * SC_LD + (4 * tx + j)] = acc[i][j];
    __syncthreads();
    if (tid < TILE) {
        double v = 0.0;
        float* outp = out + (size_t)b * F_DIM + o0 + tid;
        for (int t = 0; t < T_DIM; ++t) {
            double cu = sd[t * SC_LD + tid];
            double h = v + (cu - v) * 0.5;
            bool s = (h >= 1.0);
            outp[(size_t)t * COLS] = s ? 1.0f : 0.0f;
            v = s ? 0.0 : h;
        }
    }
}

// ------------------------------------------------------------------- launch
extern "C" void kernel_launch(void* const* d_in, const int* in_sizes, int n_in,
                              void* d_out, int out_size, void* d_ws, size_t ws_size,
                              hipStream_t stream) {
    const float* x = (const float*)d_in[0];   // [64][256][1024]
    const float* Wm = (const float*)d_in[1];  // [1024][1024]
    float* out = (float*)d_out;

    const size_t OFF_A   = 0;                                   // 64 MB
    const size_t OFF_B   = OFF_A + (size_t)M_DIM * KP * 2;      // 4 MB
    const size_t OFF_CNT = OFF_B + (size_t)F_DIM * KP * 2;
    const size_t OFF_LST = OFF_CNT + 256;
    const size_t NEEDED  = OFF_LST + (size_t)LIST_CAP * 4;

    if (ws_size < NEEDED) {
        dim3 grid(F_DIM / TILE, B_DIM, 1);
        lif_fused_kernel<<<grid, dim3(256), 0, stream>>>(x, Wm, out);
        return;
    }

    unsigned char* ws = (unsigned char*)d_ws;
    unsigned short* Abuf = (unsigned short*)(ws + OFF_A);
    unsigned short* Bbuf = (unsigned short*)(ws + OFF_B);
    unsigned int* counter = (unsigned int*)(ws + OFF_CNT);
    unsigned int* list = (unsigned int*)(ws + OFF_LST);

    split_kernel<<<dim3(16384 + 1024), dim3(256), 0, stream>>>(x, Wm, Abuf, Bbuf, counter);
    gemm_scan_kernel<<<dim3(512), dim3(512), 0, stream>>>(Abuf, Bbuf, out, counter, list);
    fixup_kernel<<<dim3(512), dim3(256), 0, stream>>>(x, Wm, counter, list, out);
}

// Round 3
// 222.528 us; speedup vs baseline: 1.0282x; 1.0282x over previous
//
#include <hip/hip_runtime.h>

// LinearLIFBlock: cur = X[16384x1024] * W^T[1024x1024]; LIF scan over t (64 steps).
// R12: R11 geometry + hardened sync. R11 (256x256 tile, wave 128x64, 2-phase
// dbuf, grid 256 = 1 block/CU) raced intermittently: first run exact, later
// fresh launches flipped spikes. The 2-phase pipeline's safety rested on hipcc
// lowering __syncthreads() to a full vmcnt drain with global_load_lds ordered
// across the barrier. R12 makes each sync point explicit and compile-time
// pinned: sched_barrier(0) -> asm s_waitcnt vmcnt(0) lgkmcnt(0) ("memory") ->
// __syncthreads() -> sched_barrier(0). No STAGE can hoist above a barrier, no
// drain can be elided. Geometry, XOR swizzle (R5/R7-validated), product order,
// LIF relay (2 batches/wave), margin 6e-5 + exact fp64 fixup all unchanged
// from R11.

#define T_DIM 64
#define B_DIM 256
#define F_DIM 1024
#define K_DIM 1024
#define M_DIM 16384            // T*B
#define COLS  (B_DIM * F_DIM)  // 262144 scan columns
#define KP    2048             // packed K: [hi | lo]
#define MARGIN 6e-5f
#define LIST_CAP 32768

typedef __attribute__((ext_vector_type(8))) short short8;
typedef __attribute__((ext_vector_type(4))) float floatx4;

#define ASYNC_CP16(gp, lp)                                                     \
    __builtin_amdgcn_global_load_lds(                                          \
        (const __attribute__((address_space(1))) unsigned int*)(gp),           \
        (__attribute__((address_space(3))) unsigned int*)(lp), 16, 0, 0)

// Hardened pipeline sync: explicit full drain + pinned ordering. Does not rely
// on hipcc's __syncthreads lowering for global_load_lds visibility.
#define HARD_SYNC() do {                                                       \
        __builtin_amdgcn_sched_barrier(0);                                     \
        asm volatile("s_waitcnt vmcnt(0) lgkmcnt(0)" ::: "memory");            \
        __syncthreads();                                                       \
        __builtin_amdgcn_sched_barrier(0);                                     \
    } while (0)

// ---------------------------------------------------------------- bf16 split
__device__ inline unsigned short f32_to_bf16_rne(float f) {
    unsigned int u = __builtin_bit_cast(unsigned int, f);
    unsigned int r = (u + 0x7FFFu + ((u >> 16) & 1u)) >> 16;
    return (unsigned short)r;
}
__device__ inline float bf16_to_f32(unsigned short h) {
    unsigned int u = ((unsigned int)h) << 16;
    return __builtin_bit_cast(float, u);
}

// Fused split: blocks [0,16384) do X (+row remap to b*64+t), [16384,17408) do W.
// Also zeroes the fixup counter (blk 0).
__global__ __launch_bounds__(256) void split_kernel(
    const float* __restrict__ x, const float* __restrict__ Wm,
    unsigned short* __restrict__ A, unsigned short* __restrict__ B,
    unsigned int* __restrict__ counter)
{
    if (blockIdx.x == 0 && threadIdx.x == 0) *counter = 0;
    const int blk = blockIdx.x;
    const float* in;
    unsigned short* dst;
    int g;
    int orow;
    if (blk < 16384) {
        g = blk * 256 + threadIdx.x;          // float4 index into x
        int e = g * 4;
        int row = e >> 10;                    // t*256 + b
        orow = ((row & 255) << 6) | (row >> 8);  // b*64 + t
        in = x; dst = A;
    } else {
        g = (blk - 16384) * 256 + threadIdx.x;
        int e = g * 4;
        orow = e >> 10;                       // o
        in = Wm; dst = B;
    }
    int k = (g * 4) & 1023;
    float4 v = reinterpret_cast<const float4*>(in)[g];
    ushort4 h, l;
    float f;
    f = v.x; h.x = f32_to_bf16_rne(f); l.x = f32_to_bf16_rne(f - bf16_to_f32(h.x));
    f = v.y; h.y = f32_to_bf16_rne(f); l.y = f32_to_bf16_rne(f - bf16_to_f32(h.y));
    f = v.z; h.z = f32_to_bf16_rne(f); l.z = f32_to_bf16_rne(f - bf16_to_f32(h.z));
    f = v.w; h.w = f32_to_bf16_rne(f); l.w = f32_to_bf16_rne(f - bf16_to_f32(h.w));
    reinterpret_cast<ushort4*>(dst)[(size_t)orow * (KP / 4) + (k >> 2)] = h;
    reinterpret_cast<ushort4*>(dst)[(size_t)orow * (KP / 4) + 256 + (k >> 2)] = l;
}

// ----------------------------------------------- fused MFMA GEMM + LIF scan
// Block tile 256(M) x 256(N); 512 threads (8 waves, 2M x 4N), wave 128x64.
// 2-phase dbuf: while computing buf[p], buf[p^1] is filled by global_load_lds
// issued BEFORE the compute phase; single hardened barrier per k-tile.
//   cur = A.hi*B.hi + A.lo*B.hi + A.hi*B.lo
__global__ __launch_bounds__(512, 2) void gemm_scan_kernel(
    const unsigned short* __restrict__ A,  // [16384][2048], rows b*64+t
    const unsigned short* __restrict__ B,  // [1024][2048],  rows o
    float* __restrict__ out,
    unsigned int* __restrict__ counter, unsigned int* __restrict__ list)
{
    __shared__ unsigned short Ah0[256 * 32], Al0[256 * 32];  // 32 KB
    __shared__ unsigned short Bh0[256 * 32], Bl0[256 * 32];  // 32 KB
    __shared__ unsigned short Ah1[256 * 32], Al1[256 * 32];  // 32 KB
    __shared__ unsigned short Bh1[256 * 32], Bl1[256 * 32];  // 32 KB

    const int tid  = threadIdx.x;
    const int lane = tid & 63;
    const int wv   = tid >> 6;                       // 0..7
    // XCD-aware: XCD = lid&7 owns 8 mt x 4 nt contiguous blocks.
    const int lid = blockIdx.x;                      // 0..255
    const int mt  = ((lid & 7) << 3) | (lid >> 5);   // 0..63
    const int nt  = (lid >> 3) & 3;                  // 0..3
    const int m0  = mt * 256;
    const int n0  = nt * 256;
    const int wm  = (wv & 1) * 128;
    const int wn  = (wv >> 1) * 64;

    floatx4 acc[8][4] = {};

    // Staging with source-side XOR chunk swizzle (R5/R7-validated: 0 conflicts).
    const int srow = tid >> 2;                      // 0..127 staging row
    const int slin = (tid & 3) * 8;                 // linear LDS chunk (dest)
    const int ssw  = (((tid & 3) ^ ((srow >> 1) & 3)) * 8);  // swizzled source chunk
    const int lrow = lane & 15;
    const int q    = lane >> 4;                     // 0..3
    const int rsw  = (lrow >> 1) & 3;               // read-side swizzle key
    const int sl   = (q ^ rsw) * 8;

    // global source pointers (per-lane, pre-swizzled); rows srow and srow+128
    const size_t RKP = (size_t)128 * KP;
    const unsigned short* ga_h = A + (size_t)(m0 + srow) * KP + ssw;
    const unsigned short* ga_l = ga_h + 1024;
    const unsigned short* gb_h = B + (size_t)(n0 + srow) * KP + ssw;
    const unsigned short* gb_l = gb_h + 1024;

    // LDS dest offsets (lane-linear within each wave: lane -> base + lane*16B)
    const int ldsA  = srow * 32 + slin;
    const int ldsA2 = (srow + 128) * 32 + slin;

    // fragment read offsets
    int aoff[8], boff[4];
#pragma unroll
    for (int i = 0; i < 8; ++i) aoff[i] = (wm + i * 16 + lrow) * 32 + sl;
#pragma unroll
    for (int j = 0; j < 4; ++j) boff[j] = (wn + j * 16 + lrow) * 32 + sl;

#define STAGE(AhB, AlB, BhB, BlB, kk) do {                                     \
        ASYNC_CP16(ga_h + (kk),       &AhB[ldsA]);                             \
        ASYNC_CP16(ga_h + RKP + (kk), &AhB[ldsA2]);                            \
        ASYNC_CP16(ga_l + (kk),       &AlB[ldsA]);                             \
        ASYNC_CP16(ga_l + RKP + (kk), &AlB[ldsA2]);                            \
        ASYNC_CP16(gb_h + (kk),       &BhB[ldsA]);                             \
        ASYNC_CP16(gb_h + RKP + (kk), &BhB[ldsA2]);                            \
        ASYNC_CP16(gb_l + (kk),       &BlB[ldsA]);                             \
        ASYNC_CP16(gb_l + RKP + (kk), &BlB[ldsA2]);                            \
    } while (0)

#define COMPUTE(AhB, AlB, BhB, BlB) do {                                       \
        short8 ah[8], al[8];                                                   \
        _Pragma("unroll")                                                      \
        for (int i = 0; i < 8; ++i) {                                          \
            ah[i] = *reinterpret_cast<const short8*>(&AhB[aoff[i]]);           \
            al[i] = *reinterpret_cast<const short8*>(&AlB[aoff[i]]);           \
        }                                                                      \
        _Pragma("unroll")                                                      \
        for (int jh = 0; jh < 2; ++jh) {                                       \
            short8 bh[2], bl[2];                                               \
            _Pragma("unroll")                                                  \
            for (int j2 = 0; j2 < 2; ++j2) {                                   \
                bh[j2] = *reinterpret_cast<const short8*>(&BhB[boff[jh * 2 + j2]]); \
                bl[j2] = *reinterpret_cast<const short8*>(&BlB[boff[jh * 2 + j2]]); \
            }                                                                  \
            __builtin_amdgcn_s_setprio(1);                                     \
            _Pragma("unroll")                                                  \
            for (int i = 0; i < 8; ++i)                                        \
                _Pragma("unroll")                                              \
                for (int j2 = 0; j2 < 2; ++j2)                                 \
                    acc[i][jh * 2 + j2] = __builtin_amdgcn_mfma_f32_16x16x32_bf16( \
                        ah[i], bh[j2], acc[i][jh * 2 + j2], 0, 0, 0);          \
            _Pragma("unroll")                                                  \
            for (int i = 0; i < 8; ++i)                                        \
                _Pragma("unroll")                                              \
                for (int j2 = 0; j2 < 2; ++j2)                                 \
                    acc[i][jh * 2 + j2] = __builtin_amdgcn_mfma_f32_16x16x32_bf16( \
                        al[i], bh[j2], acc[i][jh * 2 + j2], 0, 0, 0);          \
            _Pragma("unroll")                                                  \
            for (int i = 0; i < 8; ++i)                                        \
                _Pragma("unroll")                                              \
                for (int j2 = 0; j2 < 2; ++j2)                                 \
                    acc[i][jh * 2 + j2] = __builtin_amdgcn_mfma_f32_16x16x32_bf16( \
                        ah[i], bl[j2], acc[i][jh * 2 + j2], 0, 0, 0);          \
            __builtin_amdgcn_s_setprio(0);                                     \
        }                                                                      \
    } while (0)

    // prologue: fill buf0 for k-tile 0
    STAGE(Ah0, Al0, Bh0, Bl0, 0);
    HARD_SYNC();   // buf0 ready (explicit vmcnt(0) drain)

#pragma unroll 1
    for (int kt = 0; kt < 32; kt += 2) {
        // phase A: stage tile kt+1 into buf1, compute tile kt from buf0
        STAGE(Ah1, Al1, Bh1, Bl1, (kt + 1) * 32);
        COMPUTE(Ah0, Al0, Bh0, Bl0);
        HARD_SYNC();   // buf1 ready; buf0 free to overwrite
        // phase B: stage tile kt+2 into buf0, compute tile kt+1 from buf1
        if (kt + 2 < 32) STAGE(Ah0, Al0, Bh0, Bl0, (kt + 2) * 32);
        COMPUTE(Ah1, Al1, Bh1, Bl1);
        HARD_SYNC();
    }

#undef STAGE
#undef COMPUTE

    // ---- fused LIF scan in registers (validated relay, 2 batches/wave) ----
    // Wave rows wm..wm+127 = batches b_base, b_base+1 (64 t each).
    // acc[i][j][r] = cur at batch b_base+(i>>2), t = (i&3)*16 + q*4 + r,
    // col o = n0 + wn + j*16 + (lane&15).
    const int col = lane & 15;
    const int b_base = mt * 4 + (wv & 1) * 2;

    unsigned int fmask = 0;
#pragma unroll
    for (int hb = 0; hb < 2; ++hb) {
#pragma unroll
        for (int j = 0; j < 4; ++j) {
            float v = 0.f;
            bool fl = false;
#pragma unroll
            for (int i4 = 0; i4 < 4; ++i4) {
                const int i = hb * 4 + i4;
#pragma unroll
                for (int qq = 0; qq < 4; ++qq) {
                    if (q == qq) {
#pragma unroll
                        for (int r = 0; r < 4; ++r) {
                            float cu = acc[i][j][r];
                            float hm = v + (cu - v) * 0.5f;
                            float d = hm - 1.0f;
                            bool sp = (d >= 0.f);
                            fl |= (fabsf(d) < MARGIN);
                            acc[i][j][r] = sp ? 1.0f : 0.0f;  // spike overwrites cur
                            v = sp ? 0.f : hm;
                        }
                    }
                    v = __shfl(v, qq * 16 + col, 64);  // broadcast owner's v
                }
            }
            if (fl) fmask |= (1u << (hb * 4 + j));
        }
    }
    fmask |= __shfl_xor(fmask, 16, 64);
    fmask |= __shfl_xor(fmask, 32, 64);

    // spike stores
#pragma unroll
    for (int i = 0; i < 8; ++i) {
        float* outp = out + (size_t)(b_base + (i >> 2)) * F_DIM;
        const int tb = (i & 3) * 16 + q * 4;
#pragma unroll
        for (int j = 0; j < 4; ++j)
#pragma unroll
            for (int r = 0; r < 4; ++r)
                outp[(size_t)(tb + r) * COLS + (n0 + wn + j * 16 + col)] = acc[i][j][r];
    }

    if (q == 0 && fmask) {
        for (int hb = 0; hb < 2; ++hb)
            for (int j = 0; j < 4; ++j)
                if (fmask & (1u << (hb * 4 + j))) {
                    unsigned int idx = atomicAdd(counter, 1u);
                    if (idx < LIST_CAP)
                        list[idx] = (unsigned int)(((b_base + hb) << 10) |
                                                   (n0 + wn + j * 16 + col));
                }
    }
}

// ------------------------------------------------------- exact fp64 fixup
__global__ __launch_bounds__(256) void fixup_kernel(
    const float* __restrict__ x, const float* __restrict__ W,
    const unsigned int* __restrict__ counter, const unsigned int* __restrict__ list,
    float* __restrict__ out)
{
    __shared__ double curd[T_DIM];
    __shared__ float wrow[K_DIM];
    unsigned int n = *counter;
    if (n > LIST_CAP) n = LIST_CAP;
    const int wv = threadIdx.x >> 6, lane = threadIdx.x & 63;

    for (unsigned int idx = blockIdx.x; idx < n; idx += gridDim.x) {
        const unsigned int c = list[idx];
        const int b = c >> 10, o = c & 1023;
        __syncthreads();
        for (int k = threadIdx.x; k < K_DIM; k += 256) wrow[k] = W[(size_t)o * K_DIM + k];
        __syncthreads();
        for (int it = 0; it < 16; ++it) {
            const int t = it * 4 + wv;
            const float* xp = x + (size_t)t * COLS + (size_t)b * F_DIM + lane * 16;
            double s = 0.0;
#pragma unroll
            for (int qq = 0; qq < 4; ++qq) {
                float4 xv = reinterpret_cast<const float4*>(xp)[qq];
                float4 wq = *reinterpret_cast<const float4*>(&wrow[lane * 16 + qq * 4]);
                s += (double)xv.x * (double)wq.x + (double)xv.y * (double)wq.y +
                     (double)xv.z * (double)wq.z + (double)xv.w * (double)wq.w;
            }
#pragma unroll
            for (int off = 32; off > 0; off >>= 1) s += __shfl_down(s, off, 64);
            if (lane == 0) curd[t] = s;
        }
        __syncthreads();
        if (threadIdx.x == 0) {
            double v = 0.0;
            for (int t = 0; t < T_DIM; ++t) {
                double h = v + (curd[t] - v) * 0.5;
                bool s = (h >= 1.0);
                out[(size_t)t * COLS + c] = s ? 1.0f : 0.0f;
                v = s ? 0.0 : h;
            }
        }
        __syncthreads();
    }
}

// --------------------------------------------------- fp64 fallback (round-1)
#define TILE 64
#define KC 32
#define XS_LD 36
#define SC_LD 65

__global__ __launch_bounds__(256) void lif_fused_kernel(
    const float* __restrict__ x, const float* __restrict__ Wm, float* __restrict__ out)
{
    __shared__ __align__(16) unsigned char smem_raw[TILE * SC_LD * sizeof(double)];
    float* sf = reinterpret_cast<float*>(smem_raw);
    double* sd = reinterpret_cast<double*>(smem_raw);
    float* Xs = sf;
    float* Ws = sf + TILE * XS_LD;

    const int b = blockIdx.y;
    const int o0 = blockIdx.x * TILE;
    const int tid = threadIdx.x;
    const int tx = tid & 15, ty = tid >> 4;

    double acc[4][4];
#pragma unroll
    for (int i = 0; i < 4; ++i)
#pragma unroll
        for (int j = 0; j < 4; ++j) acc[i][j] = 0.0;

    const int r = tid >> 3, c4 = (tid & 7) * 4;
    const float* xbase = x + (size_t)b * F_DIM;

    for (int k0 = 0; k0 < K_DIM; k0 += KC) {
        __syncthreads();
        float4 xv0 = *reinterpret_cast<const float4*>(xbase + (size_t)r * COLS + k0 + c4);
        float4 xv1 = *reinterpret_cast<const float4*>(xbase + (size_t)(r + 32) * COLS + k0 + c4);
        *reinterpret_cast<float4*>(Xs + r * XS_LD + c4) = xv0;
        *reinterpret_cast<float4*>(Xs + (r + 32) * XS_LD + c4) = xv1;
        float4 wv0 = *reinterpret_cast<const float4*>(Wm + (size_t)(o0 + r) * K_DIM + k0 + c4);
        float4 wv1 = *reinterpret_cast<const float4*>(Wm + (size_t)(o0 + r + 32) * K_DIM + k0 + c4);
        *reinterpret_cast<float4*>(Ws + r * XS_LD + c4) = wv0;
        *reinterpret_cast<float4*>(Ws + (r + 32) * XS_LD + c4) = wv1;
        __syncthreads();
#pragma unroll 4
        for (int kk = 0; kk < KC; ++kk) {
            double xa[4], wb[4];
#pragma unroll
            for (int i = 0; i < 4; ++i) xa[i] = (double)Xs[(4 * ty + i) * XS_LD + kk];
#pragma unroll
            for (int j = 0; j < 4; ++j) wb[j] = (double)Ws[(4 * tx + j) * XS_LD + kk];
#pragma unroll
            for (int i = 0; i < 4; ++i)
#pragma unroll
                for (int j = 0; j < 4; ++j) acc[i][j] = fma(xa[i], wb[j], acc[i][j]);
        }
    }
    __syncthreads();
#pragma unroll
    for (int i = 0; i < 4; ++i)
#pragma unroll
        for (int j = 0; j < 4; ++j) sd[(4 * ty + i) * SC_LD + (4 * tx + j)] = acc[i][j];
    __syncthreads();
    if (tid < TILE) {
        double v = 0.0;
        float* outp = out + (size_t)b * F_DIM + o0 + tid;
        for (int t = 0; t < T_DIM; ++t) {
            double cu = sd[t * SC_LD + tid];
            double h = v + (cu - v) * 0.5;
            bool s = (h >= 1.0);
            outp[(size_t)t * COLS] = s ? 1.0f : 0.0f;
            v = s ? 0.0 : h;
        }
    }
}

// ------------------------------------------------------------------- launch
extern "C" void kernel_launch(void* const* d_in, const int* in_sizes, int n_in,
                              void* d_out, int out_size, void* d_ws, size_t ws_size,
                              hipStream_t stream) {
    const float* x = (const float*)d_in[0];   // [64][256][1024]
    const float* Wm = (const float*)d_in[1];  // [1024][1024]
    float* out = (float*)d_out;

    const size_t OFF_A   = 0;                                   // 64 MB
    const size_t OFF_B   = OFF_A + (size_t)M_DIM * KP * 2;      // 4 MB
    const size_t OFF_CNT = OFF_B + (size_t)F_DIM * KP * 2;
    const size_t OFF_LST = OFF_CNT + 256;
    const size_t NEEDED  = OFF_LST + (size_t)LIST_CAP * 4;

    if (ws_size < NEEDED) {
        dim3 grid(F_DIM / TILE, B_DIM, 1);
        lif_fused_kernel<<<grid, dim3(256), 0, stream>>>(x, Wm, out);
        return;
    }

    unsigned char* ws = (unsigned char*)d_ws;
    unsigned short* Abuf = (unsigned short*)(ws + OFF_A);
    unsigned short* Bbuf = (unsigned short*)(ws + OFF_B);
    unsigned int* counter = (unsigned int*)(ws + OFF_CNT);
    unsigned int* list = (unsigned int*)(ws + OFF_LST);

    split_kernel<<<dim3(16384 + 1024), dim3(256), 0, stream>>>(x, Wm, Abuf, Bbuf, counter);
    gemm_scan_kernel<<<dim3(256), dim3(512), 0, stream>>>(Abuf, Bbuf, out, counter, list);
    fixup_kernel<<<dim3(512), dim3(256), 0, stream>>>(x, Wm, counter, list, out);
}